// Round 18
// baseline (391.817 us; speedup 1.0000x reference)
//
#include <hip/hip_runtime.h>
#include <hip/hip_fp16.h>
#include <cstdint>
#include <cstddef>

#define N_NODES 50000
#define N_EDGES 800000
#define DIN_    768
#define H_DIM   128
#define N_REL   3
#define BETA_F  0.05f
#define SLOPE_F 0.2f

static inline int cdiv(int a, int b) { return (a + b - 1) / b; }

typedef __attribute__((ext_vector_type(8))) short bf16x8;
typedef __attribute__((ext_vector_type(8))) unsigned short u16x8;
typedef __attribute__((ext_vector_type(4))) float f32x4;

__device__ __forceinline__ unsigned short f2bf(float f) {
  unsigned u = __builtin_bit_cast(unsigned, f);
  unsigned r = (u + 0x7fffu + ((u >> 16) & 1u)) >> 16;
  return (unsigned short)r;
}
__device__ __forceinline__ float bf2f(unsigned short h) {
  unsigned u = ((unsigned)h) << 16;
  return __builtin_bit_cast(float, u);
}

#define GLOAD_LDS16(g, s) __builtin_amdgcn_global_load_lds( \
    (const __attribute__((address_space(1))) void*)(g),      \
    (__attribute__((address_space(3))) void*)(s), 16, 0, 0)

// ---------------- CSR build ----------------
__global__ void k_count(const int* __restrict__ dst, int* __restrict__ deg, int E) {
  int e = blockIdx.x * blockDim.x + threadIdx.x;
  if (e < E) atomicAdd(&deg[dst[e]], 1);
}

__global__ __launch_bounds__(256) void k_scan1(const int* __restrict__ deg,
                                               int* __restrict__ part, int n) {
  __shared__ int wsum[4];
  int i = blockIdx.x * 256 + threadIdx.x;
  int lane = threadIdx.x & 63, w = threadIdx.x >> 6;
  int v = (i < n) ? deg[i] : 0;
  #pragma unroll
  for (int d = 32; d > 0; d >>= 1) v += __shfl_xor(v, d);
  if (lane == 0) wsum[w] = v;
  __syncthreads();
  if (threadIdx.x == 0) part[blockIdx.x] = wsum[0] + wsum[1] + wsum[2] + wsum[3];
}

__global__ __launch_bounds__(256) void k_scan2(int* __restrict__ part,
                                               int* __restrict__ off, int nb, int n) {
  __shared__ int sh[256];
  int t = threadIdx.x;
  int v = (t < nb) ? part[t] : 0;
  int incl = v;
  sh[t] = incl;
  __syncthreads();
  #pragma unroll
  for (int d = 1; d < 256; d <<= 1) {
    int u = (t >= d) ? sh[t - d] : 0;
    __syncthreads();
    sh[t] += u;
    __syncthreads();
  }
  incl = sh[t];
  if (t < nb) part[t] = incl - v;
  if (t == nb - 1) off[n] = incl;
}

__global__ __launch_bounds__(256) void k_scan3(const int* __restrict__ deg,
                                               const int* __restrict__ part,
                                               int* __restrict__ off,
                                               int* __restrict__ cur, int n) {
  __shared__ int wsum[4];
  int i = blockIdx.x * 256 + threadIdx.x;
  int lane = threadIdx.x & 63, w = threadIdx.x >> 6;
  int v = (i < n) ? deg[i] : 0;
  int incl = v;
  #pragma unroll
  for (int d = 1; d < 64; d <<= 1) {
    int u = __shfl_up(incl, d);
    if (lane >= d) incl += u;
  }
  if (lane == 63) wsum[w] = incl;
  __syncthreads();
  int woff = 0;
  #pragma unroll
  for (int k = 0; k < 4; ++k) woff += (k < w) ? wsum[k] : 0;
  int ex = incl - v + woff + part[blockIdx.x];
  if (i < n) { off[i] = ex; cur[i] = ex; }
}

// fill: assign CSR slot p to edge e; record pos[e] and CSR-ordered src.
__global__ void k_fill(const int* __restrict__ dst, const int* __restrict__ src,
                       int* __restrict__ cur, int* __restrict__ pos,
                       int* __restrict__ src_s, int E) {
  int e = blockIdx.x * blockDim.x + threadIdx.x;
  if (e < E) {
    int p = atomicAdd(&cur[dst[e]], 1);
    pos[e] = p;
    src_s[p] = src[e];
  }
}

// ---------------- rel scores ----------------
__global__ __launch_bounds__(128) void k_relscore(const float* __restrict__ rel,
                                                  const float* __restrict__ Wr,
                                                  const float* __restrict__ a,
                                                  float* __restrict__ rs) {
  __shared__ float red[128];
  int k = threadIdx.x;
  for (int t = 0; t < N_REL; ++t) {
    float p = 0.f;
    #pragma unroll
    for (int j = 0; j < 32; ++j) p += rel[t * 32 + j] * Wr[j * H_DIM + k];
    red[k] = p * a[2 * H_DIM + k];
    __syncthreads();
    for (int s = 64; s > 0; s >>= 1) {
      if (k < s) red[k] += red[k + s];
      __syncthreads();
    }
    if (k == 0) rs[t] = red[0];
    __syncthreads();
  }
}

// ---------------- weight prep: W[K][128] -> BK=64-tiled, swizzled bf16 hi/lo ----------------
__global__ void k_prep(const float* __restrict__ W, int K,
                       short* __restrict__ th, short* __restrict__ tl) {
  int id = blockIdx.x * 256 + threadIdx.x;
  if (id >= K * 128) return;
  int k = id >> 7, c = id & 127;
  float w = W[id];
  unsigned short h = f2bf(w);
  unsigned short l = f2bf(w - bf2f(h));
  int kt = k >> 6;
  int g = (k >> 3) & 7;
  int j = k & 7;
  int p = g ^ (c & 7);
  size_t pos = ((size_t)(kt * 128 + c) << 6) + (p << 3) + j;
  th[pos] = (short)h;
  tl[pos] = (short)l;
}

// ---------------- m97-style split-bf16 MFMA GEMM + fused score epilogue ----------------
// R15-verified structure; single delta: B-lo NOT staged in LDS, read from pre-swizzled
// global tiles (L2-hot; R8-verified addressing). LDS 33KB -> 4 blocks/CU.
template <bool BIASRELU, bool W16, bool SCORES>
__global__ __launch_bounds__(256, 4) void k_gemm_mfma(const float* __restrict__ A,
                                                      const short* __restrict__ Bswh,
                                                      const short* __restrict__ Bswl,
                                                      const float* __restrict__ bias,
                                                      const float* __restrict__ av,
                                                      float* __restrict__ C,
                                                      __half* __restrict__ C16,
                                                      float* __restrict__ ni,
                                                      float* __restrict__ nj,
                                                      int n, int K) {
  __shared__ __align__(16) char Asm[16384];   // [64 r][64 k] f32, 32B-pair swizzle
  __shared__ __align__(16) char Bhs[16384];   // [128 c][64 k] bf16 hi, 16B swizzle
  __shared__ float nip[2][64], njp[2][64];
  int t = threadIdx.x;
  int l = t & 63, wid = t >> 6;
  int wr = wid >> 1, wc = wid & 1;
  int lr = l & 15, lk = l >> 4;
  int row0 = blockIdx.x * 64;

  f32x4 acc[2][4];
  #pragma unroll
  for (int m = 0; m < 2; ++m)
    #pragma unroll
    for (int nn = 0; nn < 4; ++nn) acc[m][nn] = (f32x4)(0.f);

  const int nt = K >> 6;

  int a_r[4], a_gl[4];
  #pragma unroll
  for (int i = 0; i < 4; ++i) {
    int id = (wid * 4 + i) * 64 + l;       // 16B slot index, 0..1023
    int r = id >> 4, s = id & 15;
    int p32 = s >> 1, b = s & 1;
    a_r[i] = r;
    a_gl[i] = (((p32 ^ (r & 7)) << 1) | b);
  }

  for (int it = 0; it < nt; ++it) {
    int k0 = it << 6;
    #pragma unroll
    for (int i = 0; i < 4; ++i) {
      int gr = row0 + a_r[i]; if (gr >= n) gr = n - 1;
      const float* srcp = A + (size_t)gr * K + k0 + a_gl[i] * 4;
      GLOAD_LDS16(srcp, Asm + (wid * 4 + i) * 1024);
    }
    const short* bh_t = Bswh + (size_t)it * 8192;
    #pragma unroll
    for (int i = 0; i < 4; ++i) {
      int id = (wid * 4 + i) * 64 + l;
      GLOAD_LDS16(bh_t + id * 8, Bhs + (wid * 4 + i) * 1024);
    }
    __syncthreads();

    const short* bl_t = Bswl + (size_t)it * 8192;   // direct from L2-hot global (R8-verified)
    #pragma unroll
    for (int kk = 0; kk < 2; ++kk) {
      int q = kk * 4 + lk;
      bf16x8 ah[2], al[2];
      #pragma unroll
      for (int m = 0; m < 2; ++m) {
        int r = wr * 32 + m * 16 + lr;
        const char* ap = Asm + r * 256 + ((q ^ (r & 7)) << 5);
        float4 f0 = *(const float4*)ap;
        float4 f1 = *(const float4*)(ap + 16);
        float ff[8] = {f0.x, f0.y, f0.z, f0.w, f1.x, f1.y, f1.z, f1.w};
        u16x8 hv, lv;
        #pragma unroll
        for (int j = 0; j < 8; ++j) {
          unsigned u = __builtin_bit_cast(unsigned, ff[j]);
          unsigned short h = (unsigned short)(u >> 16);   // truncation: exact split
          hv[j] = h;
          lv[j] = f2bf(ff[j] - bf2f(h));
        }
        ah[m] = __builtin_bit_cast(bf16x8, hv);
        al[m] = __builtin_bit_cast(bf16x8, lv);
      }
      bf16x8 bh[4], bl[4];
      #pragma unroll
      for (int nn = 0; nn < 4; ++nn) {
        int c = wc * 64 + nn * 16 + lr;
        int p = q ^ (c & 7);
        bh[nn] = *(const bf16x8*)(Bhs + c * 128 + p * 16);
        bl[nn] = *(const bf16x8*)(bl_t + (size_t)c * 64 + p * 8);
      }
      #pragma unroll
      for (int m = 0; m < 2; ++m)
        #pragma unroll
        for (int nn = 0; nn < 4; ++nn) {
          acc[m][nn] = __builtin_amdgcn_mfma_f32_16x16x32_bf16(ah[m], bh[nn], acc[m][nn], 0, 0, 0);
          acc[m][nn] = __builtin_amdgcn_mfma_f32_16x16x32_bf16(ah[m], bl[nn], acc[m][nn], 0, 0, 0);
          acc[m][nn] = __builtin_amdgcn_mfma_f32_16x16x32_bf16(al[m], bh[nn], acc[m][nn], 0, 0, 0);
        }
    }
    __syncthreads();
  }

  // ---- epilogue: C write (+fp16 copy) + optional fused scores (R15-verbatim) ----
  float avi[4], avj[4];
  if (SCORES) {
    #pragma unroll
    for (int nn = 0; nn < 4; ++nn) {
      int c = wc * 64 + nn * 16 + lr;
      avi[nn] = av[c];
      avj[nn] = av[H_DIM + c];
    }
  }
  float pi[8], pj[8];
  #pragma unroll
  for (int i = 0; i < 8; ++i) { pi[i] = 0.f; pj[i] = 0.f; }

  #pragma unroll
  for (int m = 0; m < 2; ++m) {
    int rbase = row0 + wr * 32 + m * 16 + lk * 4;
    #pragma unroll
    for (int nn = 0; nn < 4; ++nn) {
      int c = wc * 64 + nn * 16 + lr;
      #pragma unroll
      for (int q = 0; q < 4; ++q) {
        int r = rbase + q;
        float v = acc[m][nn][q];
        if (SCORES) {
          pi[m * 4 + q] += v * avi[nn];
          pj[m * 4 + q] += v * avj[nn];
        }
        if (r < n) {
          if (BIASRELU) {
            v += bias[c];
            v = v > 0.f ? v : 0.f;
          }
          C[(size_t)r * 128 + c] = v;
          if (W16) C16[(size_t)r * 128 + c] = __float2half(v);
        }
      }
    }
  }

  if (SCORES) {
    #pragma unroll
    for (int d = 1; d < 16; d <<= 1) {
      #pragma unroll
      for (int i = 0; i < 8; ++i) {
        pi[i] += __shfl_xor(pi[i], d);
        pj[i] += __shfl_xor(pj[i], d);
      }
    }
    if (lr == 0) {
      #pragma unroll
      for (int m = 0; m < 2; ++m)
        #pragma unroll
        for (int q = 0; q < 4; ++q) {
          int rl = wr * 32 + m * 16 + lk * 4 + q;
          nip[wc][rl] = pi[m * 4 + q];
          njp[wc][rl] = pj[m * 4 + q];
        }
    }
    __syncthreads();
    if (t < 64) {
      int r = row0 + t;
      if (r < n) {
        ni[r] = nip[0][t] + nip[1][t];
        nj[r] = njp[0][t] + njp[1][t];
      }
    }
  }
}

// ---------------- edge logits (scatter into CSR order) ----------------
__global__ void k_logit(const int* __restrict__ src, const int* __restrict__ dst,
                        const int* __restrict__ et,
                        const float* __restrict__ ni, const float* __restrict__ nj,
                        const float* __restrict__ rs, const int* __restrict__ pos,
                        float* __restrict__ logit_s, int E) {
  int e = blockIdx.x * blockDim.x + threadIdx.x;
  if (e >= E) return;
  float v = ni[dst[e]] + nj[src[e]] + rs[et[e]];
  logit_s[pos[e]] = v > 0.f ? v : SLOPE_F * v;
}

// ---------------- per-dst softmax + aggregate (fp16 gather) + ELU (R15-verified) ----------------
template <int LAYER>
__global__ __launch_bounds__(128) void k_aggregate(const int* __restrict__ off,
                                                   const int* __restrict__ src_s,
                                                   const float* __restrict__ logit_s,
                                                   const __half* __restrict__ h16,
                                                   float* __restrict__ alpha_s,
                                                   float* __restrict__ hout, int n) {
  __shared__ float l_red[2];
  __shared__ float l_alpha[128];
  __shared__ int   l_src[128];
  int nid = blockIdx.x;
  int t = threadIdx.x;
  int lane = t & 63;
  int w = t >> 6;
  int start = off[nid];
  int deg = off[nid + 1] - start;
  float hv = 0.f;
  if (deg > 0) {
    float m = -INFINITY;
    for (int k = t; k < deg; k += 128) m = fmaxf(m, logit_s[start + k]);
    #pragma unroll
    for (int d = 32; d > 0; d >>= 1) m = fmaxf(m, __shfl_xor(m, d));
    if (lane == 0) l_red[w] = m;
    __syncthreads();
    m = fmaxf(l_red[0], l_red[1]);
    __syncthreads();
    float s = 0.f;
    for (int k = t; k < deg; k += 128) s += expf(logit_s[start + k] - m);
    #pragma unroll
    for (int d = 32; d > 0; d >>= 1) s += __shfl_xor(s, d);
    if (lane == 0) l_red[w] = s;
    __syncthreads();
    float denom = l_red[0] + l_red[1] + 1e-16f;
    for (int base = 0; base < deg; base += 128) {
      int kk = base + t;
      if (kk < deg) {
        float al = expf(logit_s[start + kk] - m) / denom;
        if (LAYER == 1) {
          al = al * (1.f - BETA_F) + BETA_F * alpha_s[start + kk];
        } else {
          alpha_s[start + kk] = al;
        }
        l_alpha[t] = al;
        l_src[t] = src_s[start + kk];
      }
      __syncthreads();
      int cnt = deg - base; if (cnt > 128) cnt = 128;
      #pragma unroll 4
      for (int k = 0; k < cnt; ++k)
        hv += l_alpha[k] * __half2float(h16[(size_t)l_src[k] * H_DIM + t]);
      __syncthreads();
    }
  }
  hout[(size_t)nid * H_DIM + t] = hv > 0.f ? hv : expm1f(hv);
}

// ---------------- final 128->2 projection (R15-verified) ----------------
__global__ __launch_bounds__(256) void k_out(const float* __restrict__ P,
                                             const float* __restrict__ ow,
                                             const float* __restrict__ ob,
                                             float* __restrict__ out, int n) {
  int lane = threadIdx.x & 63;
  int w = threadIdx.x >> 6;
  int row = blockIdx.x * 4 + w;
  if (row >= n) return;
  float2 v  = ((const float2*)(P + (size_t)row * H_DIM))[lane];
  float2 w0 = ((const float2*)ow)[2 * lane];
  float2 w1 = ((const float2*)ow)[2 * lane + 1];
  float s0 = v.x * w0.x + v.y * w1.x;
  float s1 = v.x * w0.y + v.y * w1.y;
  #pragma unroll
  for (int d = 32; d > 0; d >>= 1) {
    s0 += __shfl_xor(s0, d);
    s1 += __shfl_xor(s1, d);
  }
  if (lane == 0) {
    out[row * 2]     = s0 + ob[0];
    out[row * 2 + 1] = s1 + ob[1];
  }
}

extern "C" void kernel_launch(void* const* d_in, const int* in_sizes, int n_in,
                              void* d_out, int out_size, void* d_ws, size_t ws_size,
                              hipStream_t stream) {
  const float* x      = (const float*)d_in[0];
  const int*   ei     = (const int*)d_in[1];
  const int*   et     = (const int*)d_in[2];
  const float* W0     = (const float*)d_in[3];
  const float* Wr0    = (const float*)d_in[4];
  const float* a0     = (const float*)d_in[5];
  const float* rel0   = (const float*)d_in[6];
  const float* W1     = (const float*)d_in[7];
  const float* Wr1    = (const float*)d_in[8];
  const float* a1     = (const float*)d_in[9];
  const float* rel1   = (const float*)d_in[10];
  const float* pool_w = (const float*)d_in[11];
  const float* pool_b = (const float*)d_in[12];
  const float* out_w  = (const float*)d_in[13];
  const float* out_b  = (const float*)d_in[14];

  const int* src = ei;
  const int* dst = ei + N_EDGES;

  char* p = (char*)d_ws;
  auto take = [&](size_t bytes) {
    char* r = p;
    p += (bytes + 511) & ~(size_t)511;
    return r;
  };
  int*   deg     = (int*)take((size_t)N_NODES * 4);
  int*   off     = (int*)take((size_t)(N_NODES + 1) * 4);
  int*   cur     = (int*)take((size_t)N_NODES * 4);
  int*   part    = (int*)take((size_t)256 * 4);
  int*   pos     = (int*)take((size_t)N_EDGES * 4);
  int*   src_s   = (int*)take((size_t)N_EDGES * 4);
  float* logit_s = (float*)take((size_t)N_EDGES * 4);
  float* alpha_s = (float*)take((size_t)N_EDGES * 4);
  float* ni      = (float*)take((size_t)N_NODES * 4);
  float* nj      = (float*)take((size_t)N_NODES * 4);
  float* rs      = (float*)take(256);
  short* wt0h    = (short*)take((size_t)DIN_ * 128 * 2);
  short* wt0l    = (short*)take((size_t)DIN_ * 128 * 2);
  short* wt1h    = (short*)take((size_t)128 * 128 * 2);
  short* wt1l    = (short*)take((size_t)128 * 128 * 2);
  short* wph     = (short*)take((size_t)128 * 128 * 2);
  short* wpl     = (short*)take((size_t)128 * 128 * 2);
  float* big1    = (float*)take((size_t)N_NODES * H_DIM * 4);
  float* big2    = (float*)take((size_t)N_NODES * H_DIM * 4);
  __half* h16    = (__half*)take((size_t)N_NODES * H_DIM * 2);

  const int EB = cdiv(N_EDGES, 256);
  const int GB = cdiv(N_NODES, 64);
  const int SB = cdiv(N_NODES, 256);

  // ---- CSR build ----
  hipMemsetAsync(deg, 0, (size_t)N_NODES * 4, stream);
  k_count<<<EB, 256, 0, stream>>>(dst, deg, N_EDGES);
  k_scan1<<<SB, 256, 0, stream>>>(deg, part, N_NODES);
  k_scan2<<<1, 256, 0, stream>>>(part, off, SB, N_NODES);
  k_scan3<<<SB, 256, 0, stream>>>(deg, part, off, cur, N_NODES);
  k_fill<<<EB, 256, 0, stream>>>(dst, src, cur, pos, src_s, N_EDGES);

  // ---- weight prep (transpose + bf16 hi/lo split + BK=64 tile/swizzle) ----
  k_prep<<<cdiv(DIN_ * 128, 256), 256, 0, stream>>>(W0, DIN_, wt0h, wt0l);
  k_prep<<<cdiv(128 * 128, 256), 256, 0, stream>>>(W1, 128, wt1h, wt1l);
  k_prep<<<cdiv(128 * 128, 256), 256, 0, stream>>>(pool_w, 128, wph, wpl);

  // ---- layer 0 ----
  k_relscore<<<1, 128, 0, stream>>>(rel0, Wr0, a0, rs);
  k_gemm_mfma<false, true, true><<<GB, 256, 0, stream>>>(x, wt0h, wt0l, nullptr, a0,
                                                         big1, h16, ni, nj, N_NODES, DIN_);
  k_logit<<<EB, 256, 0, stream>>>(src, dst, et, ni, nj, rs, pos, logit_s, N_EDGES);
  k_aggregate<0><<<N_NODES, 128, 0, stream>>>(off, src_s, logit_s, h16, alpha_s, big2, N_NODES);

  // ---- layer 1 ----
  k_relscore<<<1, 128, 0, stream>>>(rel1, Wr1, a1, rs);
  k_gemm_mfma<false, true, true><<<GB, 256, 0, stream>>>(big2, wt1h, wt1l, nullptr, a1,
                                                         big1, h16, ni, nj, N_NODES, 128);
  k_logit<<<EB, 256, 0, stream>>>(src, dst, et, ni, nj, rs, pos, logit_s, N_EDGES);
  k_aggregate<1><<<N_NODES, 128, 0, stream>>>(off, src_s, logit_s, h16, alpha_s, big2, N_NODES);

  // ---- head ----
  k_gemm_mfma<true, false, false><<<GB, 256, 0, stream>>>(big2, wph, wpl, pool_b, nullptr,
                                                          big1, nullptr, nullptr, nullptr,
                                                          N_NODES, 128);
  k_out<<<cdiv(N_NODES, 4), 256, 0, stream>>>(big1, out_w, out_b, (float*)d_out, N_NODES);
}

// Round 19
// 361.758 us; speedup vs baseline: 1.0831x; 1.0831x over previous
//
#include <hip/hip_runtime.h>
#include <hip/hip_fp16.h>
#include <cstdint>
#include <cstddef>

#define N_NODES 50000
#define N_EDGES 800000
#define DIN_    768
#define H_DIM   128
#define N_REL   3
#define BETA_F  0.05f
#define SLOPE_F 0.2f

static inline int cdiv(int a, int b) { return (a + b - 1) / b; }

typedef __attribute__((ext_vector_type(8))) short bf16x8;
typedef __attribute__((ext_vector_type(8))) unsigned short u16x8;
typedef __attribute__((ext_vector_type(4))) float f32x4;

__device__ __forceinline__ unsigned short f2bf(float f) {
  unsigned u = __builtin_bit_cast(unsigned, f);
  unsigned r = (u + 0x7fffu + ((u >> 16) & 1u)) >> 16;
  return (unsigned short)r;
}
__device__ __forceinline__ float bf2f(unsigned short h) {
  unsigned u = ((unsigned)h) << 16;
  return __builtin_bit_cast(float, u);
}

#define GLOAD_LDS16(g, s) __builtin_amdgcn_global_load_lds( \
    (const __attribute__((address_space(1))) void*)(g),      \
    (__attribute__((address_space(3))) void*)(s), 16, 0, 0)

// ---------------- CSR build ----------------
__global__ void k_count(const int* __restrict__ dst, int* __restrict__ deg, int E) {
  int e = blockIdx.x * blockDim.x + threadIdx.x;
  if (e < E) atomicAdd(&deg[dst[e]], 1);
}

__global__ __launch_bounds__(256) void k_scan1(const int* __restrict__ deg,
                                               int* __restrict__ part, int n) {
  __shared__ int wsum[4];
  int i = blockIdx.x * 256 + threadIdx.x;
  int lane = threadIdx.x & 63, w = threadIdx.x >> 6;
  int v = (i < n) ? deg[i] : 0;
  #pragma unroll
  for (int d = 32; d > 0; d >>= 1) v += __shfl_xor(v, d);
  if (lane == 0) wsum[w] = v;
  __syncthreads();
  if (threadIdx.x == 0) part[blockIdx.x] = wsum[0] + wsum[1] + wsum[2] + wsum[3];
}

__global__ __launch_bounds__(256) void k_scan2(int* __restrict__ part,
                                               int* __restrict__ off, int nb, int n) {
  __shared__ int sh[256];
  int t = threadIdx.x;
  int v = (t < nb) ? part[t] : 0;
  int incl = v;
  sh[t] = incl;
  __syncthreads();
  #pragma unroll
  for (int d = 1; d < 256; d <<= 1) {
    int u = (t >= d) ? sh[t - d] : 0;
    __syncthreads();
    sh[t] += u;
    __syncthreads();
  }
  incl = sh[t];
  if (t < nb) part[t] = incl - v;
  if (t == nb - 1) off[n] = incl;
}

__global__ __launch_bounds__(256) void k_scan3(const int* __restrict__ deg,
                                               const int* __restrict__ part,
                                               int* __restrict__ off,
                                               int* __restrict__ cur, int n) {
  __shared__ int wsum[4];
  int i = blockIdx.x * 256 + threadIdx.x;
  int lane = threadIdx.x & 63, w = threadIdx.x >> 6;
  int v = (i < n) ? deg[i] : 0;
  int incl = v;
  #pragma unroll
  for (int d = 1; d < 64; d <<= 1) {
    int u = __shfl_up(incl, d);
    if (lane >= d) incl += u;
  }
  if (lane == 63) wsum[w] = incl;
  __syncthreads();
  int woff = 0;
  #pragma unroll
  for (int k = 0; k < 4; ++k) woff += (k < w) ? wsum[k] : 0;
  int ex = incl - v + woff + part[blockIdx.x];
  if (i < n) { off[i] = ex; cur[i] = ex; }
}

// fill: assign CSR slot p to edge e; record pos[e] and CSR-ordered src.
__global__ void k_fill(const int* __restrict__ dst, const int* __restrict__ src,
                       int* __restrict__ cur, int* __restrict__ pos,
                       int* __restrict__ src_s, int E) {
  int e = blockIdx.x * blockDim.x + threadIdx.x;
  if (e < E) {
    int p = atomicAdd(&cur[dst[e]], 1);
    pos[e] = p;
    src_s[p] = src[e];
  }
}

// ---------------- rel scores ----------------
__global__ __launch_bounds__(128) void k_relscore(const float* __restrict__ rel,
                                                  const float* __restrict__ Wr,
                                                  const float* __restrict__ a,
                                                  float* __restrict__ rs) {
  __shared__ float red[128];
  int k = threadIdx.x;
  for (int t = 0; t < N_REL; ++t) {
    float p = 0.f;
    #pragma unroll
    for (int j = 0; j < 32; ++j) p += rel[t * 32 + j] * Wr[j * H_DIM + k];
    red[k] = p * a[2 * H_DIM + k];
    __syncthreads();
    for (int s = 64; s > 0; s >>= 1) {
      if (k < s) red[k] += red[k + s];
      __syncthreads();
    }
    if (k == 0) rs[t] = red[0];
    __syncthreads();
  }
}

// ---------------- weight prep: W[K][128] -> BK=64-tiled, swizzled bf16 hi/lo ----------------
__global__ void k_prep(const float* __restrict__ W, int K,
                       short* __restrict__ th, short* __restrict__ tl) {
  int id = blockIdx.x * 256 + threadIdx.x;
  if (id >= K * 128) return;
  int k = id >> 7, c = id & 127;
  float w = W[id];
  unsigned short h = f2bf(w);
  unsigned short l = f2bf(w - bf2f(h));
  int kt = k >> 6;
  int g = (k >> 3) & 7;
  int j = k & 7;
  int p = g ^ (c & 7);
  size_t pos = ((size_t)(kt * 128 + c) << 6) + (p << 3) + j;
  th[pos] = (short)h;
  tl[pos] = (short)l;
}

// ---------------- m97-style split-bf16 MFMA GEMM + fused score epilogue ----------------
// R15-verified structure. WRITEC=false skips the (dead) f32 C store.
template <bool BIASRELU, bool W16, bool WRITEC, bool SCORES>
__global__ __launch_bounds__(256, 3) void k_gemm_mfma(const float* __restrict__ A,
                                                      const short* __restrict__ Bswh,
                                                      const short* __restrict__ Bswl,
                                                      const float* __restrict__ bias,
                                                      const float* __restrict__ av,
                                                      float* __restrict__ C,
                                                      __half* __restrict__ C16,
                                                      float* __restrict__ ni,
                                                      float* __restrict__ nj,
                                                      int n, int K) {
  __shared__ __align__(16) char Asm[16384];   // [64 r][64 k] f32, 32B-pair swizzle
  __shared__ __align__(16) char Bhs[16384];   // [128 c][64 k] bf16 hi, 16B swizzle
  __shared__ __align__(16) char Bls[16384];
  __shared__ float nip[2][64], njp[2][64];
  int t = threadIdx.x;
  int l = t & 63, wid = t >> 6;
  int wr = wid >> 1, wc = wid & 1;
  int lr = l & 15, lk = l >> 4;
  int row0 = blockIdx.x * 64;

  f32x4 acc[2][4];
  #pragma unroll
  for (int m = 0; m < 2; ++m)
    #pragma unroll
    for (int nn = 0; nn < 4; ++nn) acc[m][nn] = (f32x4)(0.f);

  const int nt = K >> 6;

  int a_r[4], a_gl[4];
  #pragma unroll
  for (int i = 0; i < 4; ++i) {
    int id = (wid * 4 + i) * 64 + l;       // 16B slot index, 0..1023
    int r = id >> 4, s = id & 15;
    int p32 = s >> 1, b = s & 1;
    a_r[i] = r;
    a_gl[i] = (((p32 ^ (r & 7)) << 1) | b);
  }

  for (int it = 0; it < nt; ++it) {
    int k0 = it << 6;
    #pragma unroll
    for (int i = 0; i < 4; ++i) {
      int gr = row0 + a_r[i]; if (gr >= n) gr = n - 1;
      const float* srcp = A + (size_t)gr * K + k0 + a_gl[i] * 4;
      GLOAD_LDS16(srcp, Asm + (wid * 4 + i) * 1024);
    }
    const short* bh_t = Bswh + (size_t)it * 8192;
    const short* bl_t = Bswl + (size_t)it * 8192;
    #pragma unroll
    for (int i = 0; i < 4; ++i) {
      int id = (wid * 4 + i) * 64 + l;
      GLOAD_LDS16(bh_t + id * 8, Bhs + (wid * 4 + i) * 1024);
    }
    #pragma unroll
    for (int i = 0; i < 4; ++i) {
      int id = (wid * 4 + i) * 64 + l;
      GLOAD_LDS16(bl_t + id * 8, Bls + (wid * 4 + i) * 1024);
    }
    __syncthreads();

    #pragma unroll
    for (int kk = 0; kk < 2; ++kk) {
      int q = kk * 4 + lk;
      bf16x8 ah[2], al[2];
      #pragma unroll
      for (int m = 0; m < 2; ++m) {
        int r = wr * 32 + m * 16 + lr;
        const char* ap = Asm + r * 256 + ((q ^ (r & 7)) << 5);
        float4 f0 = *(const float4*)ap;
        float4 f1 = *(const float4*)(ap + 16);
        float ff[8] = {f0.x, f0.y, f0.z, f0.w, f1.x, f1.y, f1.z, f1.w};
        u16x8 hv, lv;
        #pragma unroll
        for (int j = 0; j < 8; ++j) {
          unsigned u = __builtin_bit_cast(unsigned, ff[j]);
          unsigned short h = (unsigned short)(u >> 16);   // truncation: exact split
          hv[j] = h;
          lv[j] = f2bf(ff[j] - bf2f(h));
        }
        ah[m] = __builtin_bit_cast(bf16x8, hv);
        al[m] = __builtin_bit_cast(bf16x8, lv);
      }
      bf16x8 bh[4], bl[4];
      #pragma unroll
      for (int nn = 0; nn < 4; ++nn) {
        int c = wc * 64 + nn * 16 + lr;
        int p = q ^ (c & 7);
        bh[nn] = *(const bf16x8*)(Bhs + c * 128 + p * 16);
        bl[nn] = *(const bf16x8*)(Bls + c * 128 + p * 16);
      }
      #pragma unroll
      for (int m = 0; m < 2; ++m)
        #pragma unroll
        for (int nn = 0; nn < 4; ++nn) {
          acc[m][nn] = __builtin_amdgcn_mfma_f32_16x16x32_bf16(ah[m], bh[nn], acc[m][nn], 0, 0, 0);
          acc[m][nn] = __builtin_amdgcn_mfma_f32_16x16x32_bf16(ah[m], bl[nn], acc[m][nn], 0, 0, 0);
          acc[m][nn] = __builtin_amdgcn_mfma_f32_16x16x32_bf16(al[m], bh[nn], acc[m][nn], 0, 0, 0);
        }
    }
    __syncthreads();
  }

  // ---- epilogue: optional C write (+fp16 copy) + optional fused scores ----
  float avi[4], avj[4];
  if (SCORES) {
    #pragma unroll
    for (int nn = 0; nn < 4; ++nn) {
      int c = wc * 64 + nn * 16 + lr;
      avi[nn] = av[c];
      avj[nn] = av[H_DIM + c];
    }
  }
  float pi[8], pj[8];
  #pragma unroll
  for (int i = 0; i < 8; ++i) { pi[i] = 0.f; pj[i] = 0.f; }

  #pragma unroll
  for (int m = 0; m < 2; ++m) {
    int rbase = row0 + wr * 32 + m * 16 + lk * 4;
    #pragma unroll
    for (int nn = 0; nn < 4; ++nn) {
      int c = wc * 64 + nn * 16 + lr;
      #pragma unroll
      for (int q = 0; q < 4; ++q) {
        int r = rbase + q;
        float v = acc[m][nn][q];
        if (SCORES) {
          pi[m * 4 + q] += v * avi[nn];
          pj[m * 4 + q] += v * avj[nn];
        }
        if (r < n) {
          if (BIASRELU) {
            v += bias[c];
            v = v > 0.f ? v : 0.f;
          }
          if (WRITEC) C[(size_t)r * 128 + c] = v;
          if (W16) C16[(size_t)r * 128 + c] = __float2half(v);
        }
      }
    }
  }

  if (SCORES) {
    #pragma unroll
    for (int d = 1; d < 16; d <<= 1) {
      #pragma unroll
      for (int i = 0; i < 8; ++i) {
        pi[i] += __shfl_xor(pi[i], d);
        pj[i] += __shfl_xor(pj[i], d);
      }
    }
    if (lr == 0) {
      #pragma unroll
      for (int m = 0; m < 2; ++m)
        #pragma unroll
        for (int q = 0; q < 4; ++q) {
          int rl = wr * 32 + m * 16 + lk * 4 + q;
          nip[wc][rl] = pi[m * 4 + q];
          njp[wc][rl] = pj[m * 4 + q];
        }
    }
    __syncthreads();
    if (t < 64) {
      int r = row0 + t;
      if (r < n) {
        ni[r] = nip[0][t] + nip[1][t];
        nj[r] = njp[0][t] + njp[1][t];
      }
    }
  }
}

// ---------------- edge logits (scatter into CSR order) ----------------
__global__ void k_logit(const int* __restrict__ src, const int* __restrict__ dst,
                        const int* __restrict__ et,
                        const float* __restrict__ ni, const float* __restrict__ nj,
                        const float* __restrict__ rs, const int* __restrict__ pos,
                        float* __restrict__ logit_s, int E) {
  int e = blockIdx.x * blockDim.x + threadIdx.x;
  if (e >= E) return;
  float v = ni[dst[e]] + nj[src[e]] + rs[et[e]];
  logit_s[pos[e]] = v > 0.f ? v : SLOPE_F * v;
}

// ---------------- per-dst softmax + aggregate (fp16 gather) + ELU (R15-verified) ----------------
template <int LAYER>
__global__ __launch_bounds__(128) void k_aggregate(const int* __restrict__ off,
                                                   const int* __restrict__ src_s,
                                                   const float* __restrict__ logit_s,
                                                   const __half* __restrict__ h16,
                                                   float* __restrict__ alpha_s,
                                                   float* __restrict__ hout, int n) {
  __shared__ float l_red[2];
  __shared__ float l_alpha[128];
  __shared__ int   l_src[128];
  int nid = blockIdx.x;
  int t = threadIdx.x;
  int lane = t & 63;
  int w = t >> 6;
  int start = off[nid];
  int deg = off[nid + 1] - start;
  float hv = 0.f;
  if (deg > 0) {
    float m = -INFINITY;
    for (int k = t; k < deg; k += 128) m = fmaxf(m, logit_s[start + k]);
    #pragma unroll
    for (int d = 32; d > 0; d >>= 1) m = fmaxf(m, __shfl_xor(m, d));
    if (lane == 0) l_red[w] = m;
    __syncthreads();
    m = fmaxf(l_red[0], l_red[1]);
    __syncthreads();
    float s = 0.f;
    for (int k = t; k < deg; k += 128) s += expf(logit_s[start + k] - m);
    #pragma unroll
    for (int d = 32; d > 0; d >>= 1) s += __shfl_xor(s, d);
    if (lane == 0) l_red[w] = s;
    __syncthreads();
    float denom = l_red[0] + l_red[1] + 1e-16f;
    for (int base = 0; base < deg; base += 128) {
      int kk = base + t;
      if (kk < deg) {
        float al = expf(logit_s[start + kk] - m) / denom;
        if (LAYER == 1) {
          al = al * (1.f - BETA_F) + BETA_F * alpha_s[start + kk];
        } else {
          alpha_s[start + kk] = al;
        }
        l_alpha[t] = al;
        l_src[t] = src_s[start + kk];
      }
      __syncthreads();
      int cnt = deg - base; if (cnt > 128) cnt = 128;
      #pragma unroll 4
      for (int k = 0; k < cnt; ++k)
        hv += l_alpha[k] * __half2float(h16[(size_t)l_src[k] * H_DIM + t]);
      __syncthreads();
    }
  }
  hout[(size_t)nid * H_DIM + t] = hv > 0.f ? hv : expm1f(hv);
}

// ---------------- final 128->2 projection (R15-verified) ----------------
__global__ __launch_bounds__(256) void k_out(const float* __restrict__ P,
                                             const float* __restrict__ ow,
                                             const float* __restrict__ ob,
                                             float* __restrict__ out, int n) {
  int lane = threadIdx.x & 63;
  int w = threadIdx.x >> 6;
  int row = blockIdx.x * 4 + w;
  if (row >= n) return;
  float2 v  = ((const float2*)(P + (size_t)row * H_DIM))[lane];
  float2 w0 = ((const float2*)ow)[2 * lane];
  float2 w1 = ((const float2*)ow)[2 * lane + 1];
  float s0 = v.x * w0.x + v.y * w1.x;
  float s1 = v.x * w0.y + v.y * w1.y;
  #pragma unroll
  for (int d = 32; d > 0; d >>= 1) {
    s0 += __shfl_xor(s0, d);
    s1 += __shfl_xor(s1, d);
  }
  if (lane == 0) {
    out[row * 2]     = s0 + ob[0];
    out[row * 2 + 1] = s1 + ob[1];
  }
}

extern "C" void kernel_launch(void* const* d_in, const int* in_sizes, int n_in,
                              void* d_out, int out_size, void* d_ws, size_t ws_size,
                              hipStream_t stream) {
  const float* x      = (const float*)d_in[0];
  const int*   ei     = (const int*)d_in[1];
  const int*   et     = (const int*)d_in[2];
  const float* W0     = (const float*)d_in[3];
  const float* Wr0    = (const float*)d_in[4];
  const float* a0     = (const float*)d_in[5];
  const float* rel0   = (const float*)d_in[6];
  const float* W1     = (const float*)d_in[7];
  const float* Wr1    = (const float*)d_in[8];
  const float* a1     = (const float*)d_in[9];
  const float* rel1   = (const float*)d_in[10];
  const float* pool_w = (const float*)d_in[11];
  const float* pool_b = (const float*)d_in[12];
  const float* out_w  = (const float*)d_in[13];
  const float* out_b  = (const float*)d_in[14];

  const int* src = ei;
  const int* dst = ei + N_EDGES;

  char* p = (char*)d_ws;
  auto take = [&](size_t bytes) {
    char* r = p;
    p += (bytes + 511) & ~(size_t)511;
    return r;
  };
  int*   deg     = (int*)take((size_t)N_NODES * 4);
  int*   off     = (int*)take((size_t)(N_NODES + 1) * 4);
  int*   cur     = (int*)take((size_t)N_NODES * 4);
  int*   part    = (int*)take((size_t)256 * 4);
  int*   pos     = (int*)take((size_t)N_EDGES * 4);
  int*   src_s   = (int*)take((size_t)N_EDGES * 4);
  float* logit_s = (float*)take((size_t)N_EDGES * 4);
  float* alpha_s = (float*)take((size_t)N_EDGES * 4);
  float* ni      = (float*)take((size_t)N_NODES * 4);
  float* nj      = (float*)take((size_t)N_NODES * 4);
  float* rs      = (float*)take(256);
  short* wt0h    = (short*)take((size_t)DIN_ * 128 * 2);
  short* wt0l    = (short*)take((size_t)DIN_ * 128 * 2);
  short* wt1h    = (short*)take((size_t)128 * 128 * 2);
  short* wt1l    = (short*)take((size_t)128 * 128 * 2);
  short* wph     = (short*)take((size_t)128 * 128 * 2);
  short* wpl     = (short*)take((size_t)128 * 128 * 2);
  float* big1    = (float*)take((size_t)N_NODES * H_DIM * 4);
  float* big2    = (float*)take((size_t)N_NODES * H_DIM * 4);
  __half* h16    = (__half*)take((size_t)N_NODES * H_DIM * 2);

  const int EB = cdiv(N_EDGES, 256);
  const int GB = cdiv(N_NODES, 64);
  const int SB = cdiv(N_NODES, 256);

  // ---- CSR build ----
  hipMemsetAsync(deg, 0, (size_t)N_NODES * 4, stream);
  k_count<<<EB, 256, 0, stream>>>(dst, deg, N_EDGES);
  k_scan1<<<SB, 256, 0, stream>>>(deg, part, N_NODES);
  k_scan2<<<1, 256, 0, stream>>>(part, off, SB, N_NODES);
  k_scan3<<<SB, 256, 0, stream>>>(deg, part, off, cur, N_NODES);
  k_fill<<<EB, 256, 0, stream>>>(dst, src, cur, pos, src_s, N_EDGES);

  // ---- weight prep (transpose + bf16 hi/lo split + BK=64 tile/swizzle) ----
  k_prep<<<cdiv(DIN_ * 128, 256), 256, 0, stream>>>(W0, DIN_, wt0h, wt0l);
  k_prep<<<cdiv(128 * 128, 256), 256, 0, stream>>>(W1, 128, wt1h, wt1l);
  k_prep<<<cdiv(128 * 128, 256), 256, 0, stream>>>(pool_w, 128, wph, wpl);

  // ---- layer 0: GEMM (h16 + fused scores; dead f32 C skipped) ----
  k_relscore<<<1, 128, 0, stream>>>(rel0, Wr0, a0, rs);
  k_gemm_mfma<false, true, false, true><<<GB, 256, 0, stream>>>(
      x, wt0h, wt0l, nullptr, a0, big1, h16, ni, nj, N_NODES, DIN_);
  k_logit<<<EB, 256, 0, stream>>>(src, dst, et, ni, nj, rs, pos, logit_s, N_EDGES);
  k_aggregate<0><<<N_NODES, 128, 0, stream>>>(off, src_s, logit_s, h16, alpha_s, big2, N_NODES);

  // ---- layer 1 ----
  k_relscore<<<1, 128, 0, stream>>>(rel1, Wr1, a1, rs);
  k_gemm_mfma<false, true, false, true><<<GB, 256, 0, stream>>>(
      big2, wt1h, wt1l, nullptr, a1, big1, h16, ni, nj, N_NODES, 128);
  k_logit<<<EB, 256, 0, stream>>>(src, dst, et, ni, nj, rs, pos, logit_s, N_EDGES);
  k_aggregate<1><<<N_NODES, 128, 0, stream>>>(off, src_s, logit_s, h16, alpha_s, big2, N_NODES);

  // ---- head: pool GEMM (writes f32 big1) + k_out ----
  k_gemm_mfma<true, false, true, false><<<GB, 256, 0, stream>>>(
      big2, wph, wpl, pool_b, nullptr, big1, nullptr, nullptr, nullptr, N_NODES, 128);
  k_out<<<cdiv(N_NODES, 4), 256, 0, stream>>>(big1, out_w, out_b, (float*)d_out, N_NODES);
}